// Round 16
// baseline (226.642 us; speedup 1.0000x reference)
//
#include <hip/hip_runtime.h>

// ---------------------------------------------------------------------------
// ZSSR involution net, fp32. Round 16 = R15 + barrier-free single-wave e.
// e_kernel: wave = (8x8-tile quarter 4x4 px, group). 64-lane WG, all phases
// wave-internal (staging/t/w-gen/einsum/epilogue); __syncthreads on a 1-wave
// WG is immediate -> no phase lockstep across waves. Grid 4736, 14 WGs/CU by
// LDS (11KB). Partial-buffer t chain (R14) and band swizzle (R10) kept.
// Layout: x[4 g][136x136 px][16 ch] channel-last, 3-px zero border.
// ---------------------------------------------------------------------------

#define HH 130
#define SP 136               // padded row stride
#define PPL (SP*SP)          // 18496
#define GP (PPL*16)          // floats per group-plane
#define XBUF2 (4*GP)         // floats per feature buffer
#define TP1 (16900*16)       // one group-partial buffer [px][16]
#define OFF_TA (2*XBUF2)             // set A: 4 buffers
#define OFF_TB (OFF_TA + 4*TP1)      // set B: 4 buffers

// --- conv_in (3->64, 3x3, pad=2) + border zeroing + layer-0 t partials -----
__global__ __launch_bounds__(256) void conv_in_kernel(
        const float* __restrict__ inf, const float* __restrict__ W,
        const float* __restrict__ b, float* __restrict__ x0,
        float* __restrict__ x1, float* __restrict__ tpA,
        const float* __restrict__ redw0) {   // [16][64] layer 0
    const int tid = threadIdx.x;
    if (blockIdx.x >= 67) {
        int idx = ((blockIdx.x - 67)*4 + blockIdx.y)*256 + tid;
        if (idx < 3192) {                      // 1596 border px * 2 buffers
            int bsel = idx & 1, e = idx >> 1;
            int r, c;
            if (e < 816) { r = e/136; c = e%136; if (r >= 3) r += 130; }
            else { int j = e-816; r = 3 + j/6; int m = j%6; c = (m<3)? m : m+130; }
            float* base = (bsel ? x1 : x0) + ((size_t)r*SP + c)*16;
            float4 z = make_float4(0.f,0.f,0.f,0.f);
            #pragma unroll
            for (int g2 = 0; g2 < 4; ++g2)
                #pragma unroll
                for (int q = 0; q < 4; ++q)
                    *(float4*)(base + (size_t)g2*GP + q*4) = z;
        }
        return;
    }
    __shared__ float wl[448];          // [16 ch][27 taps] + bias[16]
    const int g = blockIdx.y;
    for (int i = tid; i < 448; i += 256)
        wl[i] = (i < 432) ? W[g*432 + i] : b[g*16 + (i-432)];
    __syncthreads();
    int px = blockIdx.x*256 + tid;
    int pxc = px < 16900 ? px : 16899;
    int h = pxc/130, w = pxc%130;
    float xv[27];
    #pragma unroll
    for (int i = 0; i < 3; ++i)
      #pragma unroll
      for (int ky = 0; ky < 3; ++ky) {
        int y = h - 2 + ky;
        #pragma unroll
        for (int kx = 0; kx < 3; ++kx) {
            int xx = w - 2 + kx;
            float v = 0.f;
            if ((unsigned)y < 128u && (unsigned)xx < 128u)
                v = inf[i*16384 + y*128 + xx];
            xv[i*9 + ky*3 + kx] = v;
        }
      }
    float acc[16];
    #pragma unroll
    for (int c = 0; c < 16; ++c) {
        float a = wl[432 + c];
        #pragma unroll
        for (int t = 0; t < 27; ++t) a += wl[c*27 + t] * xv[t];
        acc[c] = a;
    }
    if (px < 16900) {
        float* dst = x0 + (size_t)g*GP + ((size_t)(h+3)*SP + (w+3))*16;
        #pragma unroll
        for (int q = 0; q < 4; ++q)
            *(float4*)(dst + q*4) =
                make_float4(acc[q*4], acc[q*4+1], acc[q*4+2], acc[q*4+3]);
        // layer-0 t partial for group g (thread owns all 16 ch; s_load redw0)
        float* td = tpA + (size_t)g*TP1 + (size_t)px*16;
        #pragma unroll
        for (int rq = 0; rq < 4; ++rq) {
            float p0=0.f, p1=0.f, p2=0.f, p3=0.f;
            #pragma unroll
            for (int j = 0; j < 16; ++j) {
                float a = acc[j];
                p0 += redw0[(rq*4+0)*64 + g*16 + j]*a;
                p1 += redw0[(rq*4+1)*64 + g*16 + j]*a;
                p2 += redw0[(rq*4+2)*64 + g*16 + j]*a;
                p3 += redw0[(rq*4+3)*64 + g*16 + j]*a;
            }
            *(float4*)(td + rq*4) = make_float4(p0, p1, p2, p3);
        }
    }
}

// --- e_kernel v12: single-wave, barrier-free phases ------------------------
// grid 4736: band = wid&7, j = wid>>3 (0..591); T = band*37 + (j>>4);
// sub = j&15: g = sub>>2, quarter = sub&3 (4x4 px block of the 8x8 tile).
// Lane = (px 0..15, quad 0..3). LDS/WG: xl[4][10][10][4] 6400B +
// tlol[16*20] 1280B + wl[49*17] 3332B = 11012B -> 14 WGs/CU.
__global__ __launch_bounds__(64, 4) void e_kernel(
        const float* __restrict__ x,
        const float* __restrict__ tread,  // 4 partial bufs, this layer
        float* __restrict__ twrite,       // 4 partial bufs, next layer
        const float* __restrict__ gamma, const float* __restrict__ beta,
        const float* __restrict__ spanw,  // [4 g][49 k][16 r]
        const float* __restrict__ spanb,  // [4 g][49]
        const float* __restrict__ redwn,  // [16][64] next layer
        float* __restrict__ xout,
        const int doNext)
{
    __shared__ float xl[4][10][10][4];
    __shared__ float tlol[16*20];     // tl (raw t sums) then ol (einsum out)
    __shared__ float wl[49*17];
    const int wid = blockIdx.x;
    const int bnd = wid & 7, j = wid >> 3;
    const int T = bnd*37 + (j >> 4);
    if (T >= 289) return;
    const int sub = j & 15;
    const int g = sub >> 2, qt = sub & 3;
    const int ty = (T/17)*8 + (qt >> 1)*4, tx = (T%17)*8 + (qt & 1)*4;
    const int lane = threadIdx.x;
    const int px = lane & 15, qd = lane >> 4;      // qd: per-lane 0..3
    const int sr = px >> 2, sc = px & 3;

    // ---- stage halo 10x10 px x 16 ch (coalesced: 4 lanes = 1 px, 64B) ----
    for (int i = lane; i < 400; i += 64) {
        int q = i & 3, pp = i >> 2;
        int r = pp / 10, c = pp % 10;
        int gr = ty - 3 + r, gc = tx - 3 + c;
        gr = gr < 0 ? 0 : (gr > SP-1 ? SP-1 : gr);   // clamp -> zero border
        gc = gc < 0 ? 0 : (gc > SP-1 ? SP-1 : gc);
        float4 v = *(const float4*)(x + (size_t)g*GP
                                    + ((size_t)(gr+3)*SP + (gc+3) - 3*SP - 3
                                       + 3*SP + 3)*16 + q*4);
        // NOTE: gr/gc are already padded-buffer coords (ty,tx are unpadded
        // tile coords; +3 shift below)
        v = *(const float4*)(x + (size_t)g*GP
                             + ((size_t)(gr+3 <= SP-1 ? gr+3 : SP-1)*SP
                                + (gc+3 <= SP-1 ? gc+3 : SP-1))*16 + q*4);
        *(float4*)&xl[q][r][c][0] = v;
    }

    // ---- t: lane (px, rq=qd) sums its r-quad across the 4 group partials --
    const int hh = min(ty + sr, HH-1), ww = min(tx + sc, HH-1);
    {
        const size_t toff = ((size_t)hh*HH + ww)*16 + qd*4;
        float4 s = make_float4(0.f,0.f,0.f,0.f);
        #pragma unroll
        for (int gg = 0; gg < 4; ++gg) {
            float4 a = *(const float4*)(tread + (size_t)gg*TP1 + toff);
            s.x += a.x; s.y += a.y; s.z += a.z; s.w += a.w;
        }
        *(float4*)&tlol[px*20 + qd*4] = s;
    }
    __syncthreads();                   // 1-wave: immediate

    // ---- w-gen: lane (px, kq=qd) computes its k-chunk (13/12/12/12) ------
    {
        float t16[16];
        #pragma unroll
        for (int q = 0; q < 4; ++q) {
            float4 v = *(const float4*)&tlol[px*20 + q*4];
            t16[q*4+0] = fmaxf(gamma[q*4+0]*v.x + beta[q*4+0], 0.f);
            t16[q*4+1] = fmaxf(gamma[q*4+1]*v.y + beta[q*4+1], 0.f);
            t16[q*4+2] = fmaxf(gamma[q*4+2]*v.z + beta[q*4+2], 0.f);
            t16[q*4+3] = fmaxf(gamma[q*4+3]*v.w + beta[q*4+3], 0.f);
        }
        const float* sw = spanw + g*784;   // 4 distinct addrs/instr -> L1
        const float* sb = spanb + g*49;
        const int k0 = qd ? (qd*12 + 1) : 0;
        const int kn = qd ? 12 : 13;
        for (int jj = 0; jj < 13; ++jj) {
            if (jj < kn) {
                int k = k0 + jj;
                float a = sb[k];
                #pragma unroll
                for (int r = 0; r < 16; ++r) a += sw[k*16 + r] * t16[r];
                wl[k*17 + px] = a;
            }
        }
    }
    __syncthreads();

    // ---- einsum: 49 taps x 4 ch (lane's quad qd) ----
    float4 acc = make_float4(0.f, 0.f, 0.f, 0.f);
    #pragma unroll
    for (int i = 0; i < 7; ++i)
        #pragma unroll
        for (int jj = 0; jj < 7; ++jj) {
            float4 xv = *(const float4*)&xl[qd][sr + i][sc + jj][0];
            float wk = wl[(i*7 + jj)*17 + px];
            acc.x += wk*xv.x; acc.y += wk*xv.y;
            acc.z += wk*xv.z; acc.w += wk*xv.w;
        }

    const int h = ty + sr, w2 = tx + sc;
    const bool valid = (h < HH) && (w2 < HH);
    float4 o = make_float4(fmaxf(acc.x,0.f), fmaxf(acc.y,0.f),
                           fmaxf(acc.z,0.f), fmaxf(acc.w,0.f));
    if (valid)
        *(float4*)(xout + (size_t)g*GP
                   + ((size_t)(h+3)*SP + (w2+3))*16 + qd*4) = o;

    // ---- next-layer t partial: wave-local reduce via ol (alias tl) --------
    if (doNext) {
        __syncthreads();               // tl reads done (w-gen) -> reuse as ol
        *(float4*)&tlol[px*20 + qd*4 + (qd & 0)] = o;   // ol[px][qd*4..]
        __syncthreads();
        // lane (px, rq=qd): partial t rows rq*4..+3 over group's 16 ch
        float p0=0.f, p1=0.f, p2=0.f, p3=0.f;
        #pragma unroll
        for (int jc = 0; jc < 16; ++jc) {
            float xv = tlol[px*20 + jc];
            const int c = g*16 + jc;   // 4 distinct addrs/instr -> L1
            p0 += redwn[(qd*4+0)*64 + c]*xv;
            p1 += redwn[(qd*4+1)*64 + c]*xv;
            p2 += redwn[(qd*4+2)*64 + c]*xv;
            p3 += redwn[(qd*4+3)*64 + c]*xv;
        }
        if (valid)
            *(float4*)(twrite + (size_t)g*TP1
                       + ((size_t)h*HH + w2)*16 + qd*4) =
                make_float4(p0, p1, p2, p3);
    }
}

// --- conv_out (64->12, 3x3 valid) + PixelShuffle(2) ------------------------
__global__ __launch_bounds__(256) void conv_out_ps_kernel(
        const float* __restrict__ x, const float* __restrict__ W,
        const float* __restrict__ b, float* __restrict__ out)
{
    __shared__ float xh[64*120];   // [c][10 r][12 cl]
    __shared__ float wl[6912];     // 12*64*9
    const int tid = threadIdx.x;
    const int ty = blockIdx.y*8, tx = blockIdx.x*8;

    for (int idx = tid; idx < 6912; idx += 256) wl[idx] = W[idx];
    for (int idx = tid; idx < 1600; idx += 256) {
        int g = idx/400, rem = idx%400;
        int p100 = rem>>2, q = rem&3;
        int r = p100/10, cl = p100%10;
        float4 v = *(const float4*)(x + (size_t)g*GP
                     + ((size_t)(ty + r + 3)*SP + tx + cl + 3)*16 + q*4);
        int c0 = g*16 + q*4;
        xh[(c0+0)*120 + r*12 + cl] = v.x;
        xh[(c0+1)*120 + r*12 + cl] = v.y;
        xh[(c0+2)*120 + r*12 + cl] = v.z;
        xh[(c0+3)*120 + r*12 + cl] = v.w;
    }
    __syncthreads();

    const int wave = __builtin_amdgcn_readfirstlane(tid >> 6);
    const int lane = tid & 63;
    const int s = lane >> 2, cq = lane & 3;
    const int sr = s >> 1, pc0 = (s & 1)*4;
    float acc[3][4] = {};

    for (int c = cq*16; c < cq*16 + 16; ++c) {
        #pragma unroll
        for (int ky = 0; ky < 3; ++ky) {
            const float* xb = &xh[c*120 + (sr + ky)*12 + pc0];
            float4 xa = *(const float4*)xb;
            float2 xm = *(const float2*)(xb + 4);
            float xr[6] = {xa.x, xa.y, xa.z, xa.w, xm.x, xm.y};
            #pragma unroll
            for (int oj = 0; oj < 3; ++oj) {
                const float* wp = &wl[((wave*3 + oj)*64 + c)*9 + ky*3];
                #pragma unroll
                for (int kx = 0; kx < 3; ++kx) {
                    float wv = wp[kx];
                    #pragma unroll
                    for (int q = 0; q < 4; ++q)
                        acc[oj][q] += wv * xr[kx + q];
                }
            }
        }
    }

    #pragma unroll
    for (int oj = 0; oj < 3; ++oj)
        #pragma unroll
        for (int q = 0; q < 4; ++q) {
            float v = acc[oj][q];
            v += __shfl_xor(v, 1, 64);
            v += __shfl_xor(v, 2, 64);
            acc[oj][q] = v;
        }

    if (cq == 0) {
        #pragma unroll
        for (int oj = 0; oj < 3; ++oj) {
            int o = wave*3 + oj;
            float bo = b[o];
            int c3 = o >> 2, r = (o >> 1) & 1, s2 = o & 1;
            int h = ty + sr;
            #pragma unroll
            for (int q = 0; q < 4; ++q) {
                int w = tx + pc0 + q;
                out[c3*65536 + (2*h + r)*256 + 2*w + s2] = acc[oj][q] + bo;
            }
        }
    }
}

// ---------------------------------------------------------------------------
extern "C" void kernel_launch(void* const* d_in, const int* in_sizes, int n_in,
                              void* d_out, int out_size, void* d_ws, size_t ws_size,
                              hipStream_t stream) {
    const float* inf   = (const float*)d_in[0];
    const float* cinw  = (const float*)d_in[1];
    const float* cinb  = (const float*)d_in[2];
    const float* redw  = (const float*)d_in[3];
    const float* gam   = (const float*)d_in[4];
    const float* bet   = (const float*)d_in[5];
    const float* spw   = (const float*)d_in[6];
    const float* spb   = (const float*)d_in[7];
    const float* cow   = (const float*)d_in[8];
    const float* cob   = (const float*)d_in[9];

    float* ws = (float*)d_ws;
    float* x0 = ws;
    float* x1 = ws + XBUF2;
    float* tA = ws + OFF_TA;
    float* tB = ws + OFF_TB;

    conv_in_kernel<<<dim3(80, 4), 256, 0, stream>>>(
        inf, cinw, cinb, x0, x1, tA, redw);

    float* cur = x0; float* nxt = x1;
    for (int l = 0; l < 6; ++l) {
        const int doNext = (l < 5);
        float* tread  = (l & 1) ? tB : tA;
        float* twrite = (l & 1) ? tA : tB;
        e_kernel<<<4736, 64, 0, stream>>>(
            cur, tread, twrite,
            gam + l*16, bet + l*16,
            spw + l*3136, spb + l*196,
            redw + (doNext ? (l+1)*1024 : 0),
            nxt, doNext);
        float* t = cur; cur = nxt; nxt = t;
    }

    conv_out_ps_kernel<<<dim3(16, 16), 256, 0, stream>>>(
        cur, cow, cob, (float*)d_out);
}